// Round 11
// baseline (217.944 us; speedup 1.0000x reference)
//
#include <hip/hip_runtime.h>
#include <hip/hip_bf16.h>
#include <math.h>

// ---- problem constants ----
constexpr int BB    = 1024;
constexpr int NN    = 50;
constexpr int RR    = 1000;
constexpr int DD    = 128;
constexpr int NPOIS = 50000;
#define DEG2RADF  0.017453292519943295f
#define KHALF     0.008726646259971648f   // DEG2RAD/2
#define RSQRTD    0.08838834764831845f    // 1/sqrt(128)
#define LOG2E     1.4426950408889634f
#define LN2       0.6931471805599453f
#define DBIN_C0   4013.7373f
#define DBIN_C1   668.95621f
#define TBIN_SC   0.00625f                // 63/10080
#define PENAL     -1.0e30f                // additive mask sentinel

typedef __attribute__((ext_vector_type(8))) short bfrag8;
typedef __attribute__((ext_vector_type(4))) float f32x4;

// XOR-swizzled LDS tile addressing (shorts). Row stride 128 shorts;
// 16-B block j of row r lives at physical block j ^ (r & 7).
// All MFMA fragment-row indices are ≡ colr (mod 8), so for a fragment read of
// logical k-chunk ks the physical offset is  base + kx + ks*32  (even ks) or
// base - kx + ks*32  (odd ks), with base = colr*128 + 8*(quad^(colr&3)) and
// kx = 32*((colr>>2)&1).  Iterate LOGICAL ks: bit 2 of the physical block
// index then varies ACROSS LANES per instruction (all 32 banks covered,
// 8 lanes/bank = conflict-free minimum).  (Round 1 measured: physical-index
// iteration doubles SQ_LDS_BANK_CONFLICT.)
// REGISTER-BUDGET NOTE (rounds 8/9/10 measured): at __launch_bounds__(256,4)
// the per-wave budget is 128 UNIFIED regs = 64 arch VGPR + 64 AGPR (MFMA acc).
// The allocator pins arch at 64 and demotes/spills anything beyond — it never
// allocates 65..128 arch.  Round 8: demand >>128 -> scratch spill (FETCH
// 14->460 MB).  Rounds 9/10: Af[4][4] (64 regs) demoted to per-iter LDS
// re-reads regardless of scalar trimming.  Design rule: keep ARCH demand
// <= ~60 (B-frags 32 + transients) and ACC demand <= 64; share each Af LDS
// read across multiple MFMAs instead of trying to hoist Af.
__device__ __forceinline__ int swz128(int row, int k) {
    return row * 128 + ((((k) >> 3) ^ (row & 7)) << 3) + (k & 7);
}

__device__ __forceinline__ unsigned short f2bf(float x) {
    union { __hip_bfloat16 h; unsigned short u; } cv;
    cv.h = __float2bfloat16(x);
    return cv.u;
}

__device__ __forceinline__ float exp2_asm(float x) {   // v_exp_f32: D = 2^S0
    float r;
    asm("v_exp_f32 %0, %1" : "=v"(r) : "v"(x));
    return r;
}

__device__ __forceinline__ float fract_asm(float x) {  // D = S0 - floor(S0)
    float r;
    asm("v_fract_f32 %0, %1" : "=v"(r) : "v"(x));
    return r;
}

__device__ __forceinline__ float cos_small(float x) {
    float x2 = x * x;
    return 1.0f - 0.5f * x2 + 0.041666667f * x2 * x2;
}

// ---- precompute (merged): Mt and Gp, both bf16 with LOG2E/sqrt(D) folded ----
// Gp in MFMA B-fragment order: Gp[rt][wid][ks][lane][8], lane = quad*16+colr,
// r = rt*64 + wid*16 + colr, k = ks*32 + quad*8 + k7. Rows 1000..1023 zeroed.
__global__ void prep_mg(const float* __restrict__ Wq, const float* __restrict__ Wk,
                        const float* __restrict__ Wv, const float* __restrict__ Re,
                        unsigned short* __restrict__ Mt, unsigned short* __restrict__ Gp) {
    int k = threadIdx.x;
    if (blockIdx.x < DD) {
        int c = blockIdx.x;
        float s0 = 0.f, s1 = 0.f, s2 = 0.f, s3 = 0.f;
        for (int d = 0; d < DD; d += 4) {
            s0 += Wq[(d + 0) * DD + k] * Wk[(d + 0) * DD + c];
            s1 += Wq[(d + 1) * DD + k] * Wk[(d + 1) * DD + c];
            s2 += Wq[(d + 2) * DD + k] * Wk[(d + 2) * DD + c];
            s3 += Wq[(d + 3) * DD + k] * Wk[(d + 3) * DD + c];
        }
        Mt[c * DD + k] = f2bf((s0 + s1 + s2 + s3) * (RSQRTD * LOG2E));
    } else {
        int r = blockIdx.x - DD;
        float val = 0.f;
        if (r < RR) {
            float s0 = 0.f, s1 = 0.f, s2 = 0.f, s3 = 0.f;
            for (int d = 0; d < DD; d += 4) {
                s0 += Wv[(d + 0) * DD + k] * Re[r * DD + d + 0];
                s1 += Wv[(d + 1) * DD + k] * Re[r * DD + d + 1];
                s2 += Wv[(d + 2) * DD + k] * Re[r * DD + d + 2];
                s3 += Wv[(d + 3) * DD + k] * Re[r * DD + d + 3];
            }
            val = (s0 + s1 + s2 + s3) * (RSQRTD * LOG2E);
        }
        int rt = r >> 6, widr = (r >> 4) & 3, colr = r & 15;
        int ks = k >> 5, quad = (k >> 3) & 3, k7 = k & 7;
        int lane = quad * 16 + colr;
        Gp[((((rt * 16 + widr * 4 + ks) * 64) + lane) << 3) + k7] = f2bf(val);
    }
}

// ---- fused: per-b attention (4 MFMA phases) + match (8 outer × 2 r-tiles) ----
// Z never touches HBM: accZ registers -> swizzled LDS (reusing the dead
// ys/ps union as As) -> match loop.
__global__ __launch_bounds__(256, 4) void stan_fused(
    const int* __restrict__ poi_idx, const int* __restrict__ hourw,
    const float* __restrict__ lat, const float* __restrict__ lon,
    const float* __restrict__ tmin,
    const float* __restrict__ poi_emb, const float* __restrict__ time_emb,
    const float* __restrict__ Et_g, const float* __restrict__ Ed_g,
    const float* __restrict__ Em_g,
    const unsigned short* __restrict__ Mtb, const unsigned short* __restrict__ Gp,
    const float* __restrict__ cent, float* __restrict__ out) {
    __shared__ short xs[64 * 128];             // x bf16, swizzled, 16 KB
    __shared__ union {
        short ys[64 * 128];                    // Y bf16, swizzled, 16 KB
        short ps[64 * 64];                     // P bf16, swizzled
        short as_[64 * 128];                   // Z bf16, swizzled (match A-tile)
    } u2;
    __shared__ float2 Et2[64], Ed2[64], Em2[64];  // (e, de) * LOG2E
    __shared__ float4 bnfo[64];                // (latk, lonk, cos, t*TBIN_SC)
    __shared__ float4 bnfoM[64];               // (latk, lonk, cos, pen) for match
    __shared__ float  jpen[64];                // 0 valid / -1e30 pad
    __shared__ int2   nidx[64];                // (poi row, hour row) for gather

    const int b = blockIdx.x, tid = threadIdx.x;
    const int wid = tid >> 6, lane = tid & 63;
    const int quad = lane >> 4, colr = lane & 15;

    if (tid < 64) {
        int kk = tid > 62 ? 62 : tid;
        float t0 = Et_g[kk] * LOG2E, t1 = Et_g[kk + 1] * LOG2E;
        float d0 = Ed_g[kk] * LOG2E, d1 = Ed_g[kk + 1] * LOG2E;
        float e0 = Em_g[kk] * LOG2E, e1 = Em_g[kk + 1] * LOG2E;
        Et2[tid] = make_float2(t0, t1 - t0);
        Ed2[tid] = make_float2(d0, d1 - d0);
        Em2[tid] = make_float2(e0, e1 - e0);
        if (tid < NN) {
            int p = poi_idx[b * NN + tid];
            int pd = (p < 0);
            float la = lat[b * NN + tid], lo = lon[b * NN + tid];
            float cs = cos_small(la * DEG2RADF);
            float pen = pd ? PENAL : 0.f;
            nidx[tid] = make_int2(pd ? NPOIS : p, pd ? 0 : hourw[b * NN + tid]);
            bnfo[tid]  = make_float4(la * KHALF, lo * KHALF, cs,
                                     tmin[b * NN + tid] * TBIN_SC);
            bnfoM[tid] = make_float4(la * KHALF, lo * KHALF, cs, pen);
            jpen[tid] = pen;
        } else {
            // poi_emb[NPOIS] and time_emb[0] are all-zero rows -> x row = 0
            nidx[tid] = make_int2(NPOIS, 0);
            bnfo[tid]  = make_float4(0.f, 0.f, 1.f, 0.f);
            bnfoM[tid] = make_float4(0.f, 0.f, 1.f, PENAL);
            jpen[tid] = PENAL;
        }
    }
    __syncthreads();

    // ---- phase 1: gather x -> xs (bf16, swizzled u32 stores) ----
    for (int idx = tid; idx < 64 * 64; idx += 256) {
        int n = idx >> 6, c2 = idx & 63;       // c2 = dword index within row
        int2 ix = nidx[n];
        float2 pe = ((const float2*)(poi_emb  + (size_t)ix.x * DD))[c2];
        float2 te = ((const float2*)(time_emb + (size_t)ix.y * DD))[c2];
        unsigned pack = (unsigned)f2bf(pe.x + te.x)
                      | ((unsigned)f2bf(pe.y + te.y) << 16);
        ((unsigned*)xs)[n * 64 + (((c2 >> 2) ^ (n & 7)) << 2) + (c2 & 3)] = pack;
    }
    __syncthreads();

    // thread-constant swizzle bases (see comment at swz128)
    const int q8    = (quad ^ (colr & 3)) * 8;
    const int kx    = (colr & 4) * 8;          // ((colr>>2)&1)*32
    const int xbase = colr * 128 + q8;
    const int xe = xbase + kx, xo = xbase - kx;

    // ---- phase 2: Y = x @ Mt^T (MFMA), Mt streamed from L1/L2 ----
    {
        f32x4 accY[2][4];
        #pragma unroll
        for (int ct = 0; ct < 2; ct++)
            #pragma unroll
            for (int mt = 0; mt < 4; mt++) accY[ct][mt] = (f32x4){0.f, 0.f, 0.f, 0.f};
        #pragma unroll
        for (int ks = 0; ks < 4; ks++) {
            const int k0 = ks * 32 + quad * 8;                 // logical (global Mt read)
            const int xoff = ((ks & 1) ? xo : xe) + ks * 32;   // physical LDS offset
            bfrag8 av[4], bv[2];
            #pragma unroll
            for (int mt = 0; mt < 4; mt++)
                av[mt] = *(const bfrag8*)(&xs[xoff + mt * 2048]);
            #pragma unroll
            for (int ct = 0; ct < 2; ct++) {
                int c = wid * 32 + ct * 16 + colr;
                bv[ct] = *(const bfrag8*)(Mtb + (size_t)c * DD + k0);
            }
            #pragma unroll
            for (int ct = 0; ct < 2; ct++)
                #pragma unroll
                for (int mt = 0; mt < 4; mt++)
                    accY[ct][mt] = __builtin_amdgcn_mfma_f32_16x16x32_bf16(
                        av[mt], bv[ct], accY[ct][mt], 0, 0, 0);
        }
        #pragma unroll
        for (int ct = 0; ct < 2; ct++)
            #pragma unroll
            for (int mt = 0; mt < 4; mt++)
                #pragma unroll
                for (int reg = 0; reg < 4; reg++) {
                    int m = mt * 16 + quad * 4 + reg;
                    int c = wid * 32 + ct * 16 + colr;
                    u2.ys[swz128(m, c)] = (short)f2bf(accY[ct][mt][reg]);
                }
    }
    __syncthreads();

    // ---- phase 3: S^T = x @ Y^T (MFMA). C: row=j, col=i=wid*16+colr ----
    const int i = wid * 16 + colr;
    const int ybase = xbase + wid * 2048;
    const int ye = ybase + kx, yo = ybase - kx;
    f32x4 accS[4];
    #pragma unroll
    for (int mt = 0; mt < 4; mt++) accS[mt] = (f32x4){0.f, 0.f, 0.f, 0.f};
    #pragma unroll
    for (int ks = 0; ks < 4; ks++) {           // LOGICAL order: conflict-free
        const int yoff = ((ks & 1) ? yo : ye) + ks * 32;
        const int xoff = ((ks & 1) ? xo : xe) + ks * 32;
        bfrag8 bv = *(const bfrag8*)(&u2.ys[yoff]);
        #pragma unroll
        for (int mt = 0; mt < 4; mt++) {
            bfrag8 av = *(const bfrag8*)(&xs[xoff + mt * 2048]);
            accS[mt] = __builtin_amdgcn_mfma_f32_16x16x32_bf16(
                av, bv, accS[mt], 0, 0, 0);
        }
    }
    __syncthreads();   // ys MFMA reads done; ps may overwrite the union

    // ---- bias + softmax over j (exp2 domain; NO max pass: scores are O(1),
    // pads give exp2(-1e30)=0 exactly; f32 exp2 safe to |s|~120) ----
    {
        const float4 bi = bnfo[i];
        float sv[14];
        #pragma unroll
        for (int mt = 0; mt < 4; mt++) {
            const int nregs = (mt == 3) ? 2 : 4;
            #pragma unroll
            for (int reg = 0; reg < nregs; reg++) {
                int j = mt * 16 + quad * 4 + reg;
                float4 bj = bnfo[j];
                float tb = fabsf(bi.w - bj.w);
                int   kt = (int)tb;
                float ft = fract_asm(tb);
                float2 et = Et2[kt];
                float bt = fmaf(ft, et.y, et.x);
                float du = bi.x - bj.x, dv = bi.y - bj.y;
                float a = fmaf((bi.z * bj.z) * dv, dv, du * du);
                float x = __builtin_amdgcn_sqrtf(a);
                float db = x * fmaf(a, DBIN_C1, DBIN_C0);
                int   kd = (int)db;
                float fd = fract_asm(db);
                float2 ed = Ed2[kd];
                float bd = fmaf(fd, ed.y, ed.x);
                sv[mt * 4 + reg] = (accS[mt][reg] + bt) + (bd + jpen[j]);
            }
        }
        float l = 0.f;
        #pragma unroll
        for (int t = 0; t < 14; t++) {
            float p = exp2_asm(sv[t]);
            sv[t] = p;
            l += p;
        }
        l += __shfl_xor(l, 16, 64);
        l += __shfl_xor(l, 32, 64);
        float rl = __builtin_amdgcn_rcpf(l);
        #pragma unroll
        for (int mt = 0; mt < 4; mt++)
            #pragma unroll
            for (int rp = 0; rp < 2; rp++) {
                int j0 = mt * 16 + quad * 4 + rp * 2;
                unsigned pack;
                if (mt == 3 && rp == 1) {
                    pack = 0u;                 // always-invalid slots: P = 0
                } else {
                    unsigned lo = f2bf(sv[mt * 4 + rp * 2]     * rl);
                    unsigned hi = f2bf(sv[mt * 4 + rp * 2 + 1] * rl);
                    pack = lo | (hi << 16);
                }
                ((unsigned*)u2.ps)[i * 32 + (((j0 >> 3) ^ (i & 7)) << 2) + ((j0 & 7) >> 1)]
                    = pack;
            }
    }
    __syncthreads();

    // ---- phase 4: Z = P @ x (K=64 over j); then accZ -> As (swizzled LDS) ----
    {
        f32x4 accZ[2][4];
        #pragma unroll
        for (int nt = 0; nt < 2; nt++)
            #pragma unroll
            for (int mt = 0; mt < 4; mt++) accZ[nt][mt] = (f32x4){0.f, 0.f, 0.f, 0.f};
        union BF { unsigned u[4]; bfrag8 v; };
        const int pbase = colr * 64 + q8;
        const int pe = pbase + kx, po = pbase - kx;
        #pragma unroll
        for (int ks = 0; ks < 2; ks++) {
            const int k0 = ks * 32 + quad * 8;                 // logical (xs gather)
            const int poff = ((ks & 1) ? po : pe) + ks * 32;   // physical (ps reads)
            bfrag8 av[4];
            #pragma unroll
            for (int mt = 0; mt < 4; mt++)
                av[mt] = *(const bfrag8*)(&u2.ps[poff + mt * 1024]);
            BF bvx[2];
            #pragma unroll
            for (int nt = 0; nt < 2; nt++) {
                int d = wid * 32 + nt * 16 + colr;
                #pragma unroll
                for (int t2 = 0; t2 < 4; t2++) {
                    unsigned lo = (unsigned short)xs[swz128(k0 + 2 * t2,     d)];
                    unsigned hi = (unsigned short)xs[swz128(k0 + 2 * t2 + 1, d)];
                    bvx[nt].u[t2] = lo | (hi << 16);
                }
            }
            #pragma unroll
            for (int nt = 0; nt < 2; nt++)
                #pragma unroll
                for (int mt = 0; mt < 4; mt++)
                    accZ[nt][mt] = __builtin_amdgcn_mfma_f32_16x16x32_bf16(
                        av[mt], bvx[nt].v, accZ[nt][mt], 0, 0, 0);
        }
        __syncthreads();   // all ps reads done; as_ may overwrite the union
        #pragma unroll
        for (int mt = 0; mt < 4; mt++)
            #pragma unroll
            for (int reg = 0; reg < 4; reg++) {
                int ii = mt * 16 + quad * 4 + reg;
                #pragma unroll
                for (int nt = 0; nt < 2; nt++) {
                    int d = wid * 32 + nt * 16 + colr;
                    float zv = (ii < NN) ? accZ[nt][mt][reg] : 0.f;
                    u2.as_[swz128(ii, d)] = (short)f2bf(zv);
                }
            }
    }
    __syncthreads();

    // ---- match part: 8 outer iters × 2 r-tiles.  Each Af LDS slice is read
    // ONCE per ks and feeds TWO MFMAs (bf0/bf1, acc0/acc1): MFMA:DS ratio
    // 1:1 -> 2:1, halving the dominant LDS traffic (Af re-reads were ~20 us
    // of CU LDS-pipe time).  Arch-reg demand: bf0+bf1=32 + af transients 16
    // + addressing ~ <=60; acc0+acc1=32 AGPR — fits the 64+64 split budget. ----
    bfrag8 bf0[4], bf1[4];
    #pragma unroll
    for (int ks = 0; ks < 4; ks++) {
        bf0[ks] = *(const bfrag8*)(Gp + (size_t)(((      wid * 4 + ks) * 64 + lane) << 3));
        bf1[ks] = *(const bfrag8*)(Gp + (size_t)(((16  + wid * 4 + ks) * 64 + lane) << 3));
    }

    const int rL = wid * 16 + colr;

    #pragma unroll 1
    for (int ot = 0; ot < 8; ot++) {
        f32x4 acc0[4], acc1[4];
        #pragma unroll
        for (int mt = 0; mt < 4; mt++) {
            acc0[mt] = (f32x4){0.f, 0.f, 0.f, 0.f};
            acc1[mt] = (f32x4){0.f, 0.f, 0.f, 0.f};
        }
        #pragma unroll
        for (int ks = 0; ks < 4; ks++) {
            const int aoff = ((ks & 1) ? xo : xe) + ks * 32;
            #pragma unroll
            for (int mt = 0; mt < 4; mt++) {
                bfrag8 af = *(const bfrag8*)(&u2.as_[aoff + mt * 2048]);
                acc0[mt] = __builtin_amdgcn_mfma_f32_16x16x32_bf16(af, bf0[ks], acc0[mt], 0, 0, 0);
                acc1[mt] = __builtin_amdgcn_mfma_f32_16x16x32_bf16(af, bf1[ks], acc1[mt], 0, 0, 0);
            }
        }
        // bf0/bf1 dead — reload for the next rt pair (clamped on last iter);
        // the loads fly under the two bias/softmax blocks (~1000 cyc)
        {
            const int rn0 = (ot < 7) ? 2 * ot + 2 : 14;
            #pragma unroll
            for (int ks = 0; ks < 4; ks++) {
                bf0[ks] = *(const bfrag8*)(Gp + (size_t)((( rn0      * 16 + wid * 4 + ks) * 64 + lane) << 3));
                bf1[ks] = *(const bfrag8*)(Gp + (size_t)((((rn0 + 1) * 16 + wid * 4 + ks) * 64 + lane) << 3));
            }
        }
        // ---- two bias + softmax-weighted sums (exp2 domain; no max pass;
        // 'half' is fully unrolled -> acc select is static) ----
        #pragma unroll
        for (int half = 0; half < 2; half++) {
            const int r  = (2 * ot + half) * 64 + rL;
            const int rc = (r < RR) ? r : (RR - 1);
            float2 cc = ((const float2*)cent)[rc];
            const float rvx = cc.x * KHALF, rvy = cc.y * KHALF;
            const float rvz = cos_small(cc.x * DEG2RADF);
            float l = 0.f, aw = 0.f;
            #pragma unroll
            for (int mt = 0; mt < 4; mt++) {
                const int nregs = (mt == 3) ? 2 : 4;
                #pragma unroll
                for (int reg = 0; reg < nregs; reg++) {
                    int n = mt * 16 + quad * 4 + reg;
                    float4 bn = bnfoM[n];
                    float du = bn.x - rvx, dv = bn.y - rvy;
                    float a = fmaf((bn.z * rvz) * dv, dv, du * du);
                    float x = __builtin_amdgcn_sqrtf(a);
                    float db = x * fmaf(a, DBIN_C1, DBIN_C0);
                    int   kd = (int)db;
                    float fd = fract_asm(db);
                    float2 ed = Em2[kd];
                    float bias = fmaf(fd, ed.y, ed.x);
                    float av_ = half ? acc1[mt][reg] : acc0[mt][reg];
                    float sc = (av_ + bias) + bn.w;
                    float p = exp2_asm(sc);      // pad slots: exp2(-1e30) = 0
                    l += p;
                    aw = fmaf(p, sc, aw);        // fma(0, -1e30, aw) = aw exactly
                }
            }
            l  += __shfl_xor(l, 16, 64); aw += __shfl_xor(aw, 16, 64);
            l  += __shfl_xor(l, 32, 64); aw += __shfl_xor(aw, 32, 64);
            if (quad == 0 && r < RR)
                out[(size_t)b * RR + r] = aw * __builtin_amdgcn_rcpf(l) * LN2;
        }
    }
}

extern "C" void kernel_launch(void* const* d_in, const int* in_sizes, int n_in,
                              void* d_out, int out_size, void* d_ws, size_t ws_size,
                              hipStream_t stream) {
    const int*   poi_idx  = (const int*)d_in[0];
    const int*   hourw    = (const int*)d_in[1];
    const float* lat      = (const float*)d_in[2];
    const float* lon      = (const float*)d_in[3];
    const float* tmin     = (const float*)d_in[4];
    const float* cent     = (const float*)d_in[5];
    const float* poi_emb  = (const float*)d_in[6];
    const float* time_emb = (const float*)d_in[7];
    const float* E_t      = (const float*)d_in[8];
    const float* E_d      = (const float*)d_in[9];
    const float* E_dm     = (const float*)d_in[10];
    const float* Remb     = (const float*)d_in[11];
    const float* Wq       = (const float*)d_in[12];
    const float* Wk       = (const float*)d_in[13];
    const float* Wv       = (const float*)d_in[14];
    float* out            = (float*)d_out;

    unsigned short* Mtb = (unsigned short*)d_ws;            // 128*128 bf16 (32 KB)
    unsigned short* Gpb = Mtb + DD * DD;                    // 1024*128 bf16 (256 KB, frag order)

    prep_mg<<<dim3(DD + 1024), DD, 0, stream>>>(Wq, Wk, Wv, Remb, Mtb, Gpb);
    stan_fused<<<dim3(BB), 256, 0, stream>>>(poi_idx, hourw, lat, lon, tmin,
                                             poi_emb, time_emb, E_t, E_d, E_dm,
                                             Mtb, Gpb, cent, out);
}

// Round 12
// 162.575 us; speedup vs baseline: 1.3406x; 1.3406x over previous
//
#include <hip/hip_runtime.h>
#include <hip/hip_bf16.h>
#include <math.h>

// ---- problem constants ----
constexpr int BB    = 1024;
constexpr int NN    = 50;
constexpr int RR    = 1000;
constexpr int DD    = 128;
constexpr int NPOIS = 50000;
#define DEG2RADF  0.017453292519943295f
#define KHALF     0.008726646259971648f   // DEG2RAD/2
#define RSQRTD    0.08838834764831845f    // 1/sqrt(128)
#define LOG2E     1.4426950408889634f
#define LN2       0.6931471805599453f
#define DBIN_C0   4013.7373f
#define DBIN_C1   668.95621f
#define TBIN_SC   0.00625f                // 63/10080
#define PENAL     -1.0e30f                // additive mask sentinel

typedef __attribute__((ext_vector_type(8))) short bfrag8;
typedef __attribute__((ext_vector_type(4))) float f32x4;

// XOR-swizzled LDS tile addressing (shorts). Row stride 128 shorts;
// 16-B block j of row r lives at physical block j ^ (r & 7).
// All MFMA fragment-row indices are ≡ colr (mod 8): for logical k-chunk ks the
// physical offset is base+kx+ks*32 (even ks) / base-kx+ks*32 (odd ks), with
// base = colr*128 + 8*(quad^(colr&3)), kx = 32*((colr>>2)&1).  Iterate
// LOGICAL ks (round 1: physical-order iteration doubles bank conflicts).
// REGISTER-BUDGET NOTE (rounds 8/9/10/11 measured): at __launch_bounds__(256,4)
// budget = 128 unified = 64 arch + 64 acc; the allocator pins arch at 64 and
// spills rather than allocating 65..128 arch.  r8: Xf hoist + unroll-2 ->
// scratch (FETCH 460 MB).  r9/r10: Af[4][4] demoted to per-iter LDS reads.
// r11: bf0/bf1 (32 regs) live ACROSS the bias blocks -> bias-region demand
// ~84 arch -> spill (FETCH 248 MB).  Design rule: keep every REGION's arch
// demand <= ~60; B-fragments must die at the end of the MFMA cluster (no
// prefetch across the bias pass).
__device__ __forceinline__ int swz128(int row, int k) {
    return row * 128 + ((((k) >> 3) ^ (row & 7)) << 3) + (k & 7);
}

__device__ __forceinline__ unsigned short f2bf(float x) {
    union { __hip_bfloat16 h; unsigned short u; } cv;
    cv.h = __float2bfloat16(x);
    return cv.u;
}

__device__ __forceinline__ float exp2_asm(float x) {   // v_exp_f32: D = 2^S0
    float r;
    asm("v_exp_f32 %0, %1" : "=v"(r) : "v"(x));
    return r;
}

__device__ __forceinline__ float fract_asm(float x) {  // D = S0 - floor(S0)
    float r;
    asm("v_fract_f32 %0, %1" : "=v"(r) : "v"(x));
    return r;
}

__device__ __forceinline__ float cos_small(float x) {
    float x2 = x * x;
    return 1.0f - 0.5f * x2 + 0.041666667f * x2 * x2;
}

// ---- precompute (merged): Mt and Gp, both bf16 with LOG2E/sqrt(D) folded ----
// Gp in MFMA B-fragment order: Gp[rt][wid][ks][lane][8], lane = quad*16+colr,
// r = rt*64 + wid*16 + colr, k = ks*32 + quad*8 + k7. Rows 1000..1023 zeroed.
__global__ void prep_mg(const float* __restrict__ Wq, const float* __restrict__ Wk,
                        const float* __restrict__ Wv, const float* __restrict__ Re,
                        unsigned short* __restrict__ Mt, unsigned short* __restrict__ Gp) {
    int k = threadIdx.x;
    if (blockIdx.x < DD) {
        int c = blockIdx.x;
        float s0 = 0.f, s1 = 0.f, s2 = 0.f, s3 = 0.f;
        for (int d = 0; d < DD; d += 4) {
            s0 += Wq[(d + 0) * DD + k] * Wk[(d + 0) * DD + c];
            s1 += Wq[(d + 1) * DD + k] * Wk[(d + 1) * DD + c];
            s2 += Wq[(d + 2) * DD + k] * Wk[(d + 2) * DD + c];
            s3 += Wq[(d + 3) * DD + k] * Wk[(d + 3) * DD + c];
        }
        Mt[c * DD + k] = f2bf((s0 + s1 + s2 + s3) * (RSQRTD * LOG2E));
    } else {
        int r = blockIdx.x - DD;
        float val = 0.f;
        if (r < RR) {
            float s0 = 0.f, s1 = 0.f, s2 = 0.f, s3 = 0.f;
            for (int d = 0; d < DD; d += 4) {
                s0 += Wv[(d + 0) * DD + k] * Re[r * DD + d + 0];
                s1 += Wv[(d + 1) * DD + k] * Re[r * DD + d + 1];
                s2 += Wv[(d + 2) * DD + k] * Re[r * DD + d + 2];
                s3 += Wv[(d + 3) * DD + k] * Re[r * DD + d + 3];
            }
            val = (s0 + s1 + s2 + s3) * (RSQRTD * LOG2E);
        }
        int rt = r >> 6, widr = (r >> 4) & 3, colr = r & 15;
        int ks = k >> 5, quad = (k >> 3) & 3, k7 = k & 7;
        int lane = quad * 16 + colr;
        Gp[((((rt * 16 + widr * 4 + ks) * 64) + lane) << 3) + k7] = f2bf(val);
    }
}

// ---- fused: per-b attention (4 MFMA phases) + match (8 outer × 2 r-tiles) ----
// Z never touches HBM: accZ registers -> swizzled LDS (reusing the dead
// ys/ps union as As) -> match loop.
__global__ __launch_bounds__(256, 4) void stan_fused(
    const int* __restrict__ poi_idx, const int* __restrict__ hourw,
    const float* __restrict__ lat, const float* __restrict__ lon,
    const float* __restrict__ tmin,
    const float* __restrict__ poi_emb, const float* __restrict__ time_emb,
    const float* __restrict__ Et_g, const float* __restrict__ Ed_g,
    const float* __restrict__ Em_g,
    const unsigned short* __restrict__ Mtb, const unsigned short* __restrict__ Gp,
    const float* __restrict__ cent, float* __restrict__ out) {
    __shared__ short xs[64 * 128];             // x bf16, swizzled, 16 KB
    __shared__ union {
        short ys[64 * 128];                    // Y bf16, swizzled, 16 KB
        short ps[64 * 64];                     // P bf16, swizzled
        short as_[64 * 128];                   // Z bf16, swizzled (match A-tile)
    } u2;
    __shared__ float2 Et2[64], Ed2[64], Em2[64];  // (e, de) * LOG2E
    __shared__ float4 bnfo[64];                // (latk, lonk, cos, t*TBIN_SC)
    __shared__ float4 bnfoM[64];               // (latk, lonk, cos, pen) for match
    __shared__ float  jpen[64];                // 0 valid / -1e30 pad
    __shared__ int2   nidx[64];                // (poi row, hour row) for gather

    const int b = blockIdx.x, tid = threadIdx.x;
    const int wid = tid >> 6, lane = tid & 63;
    const int quad = lane >> 4, colr = lane & 15;

    if (tid < 64) {
        int kk = tid > 62 ? 62 : tid;
        float t0 = Et_g[kk] * LOG2E, t1 = Et_g[kk + 1] * LOG2E;
        float d0 = Ed_g[kk] * LOG2E, d1 = Ed_g[kk + 1] * LOG2E;
        float e0 = Em_g[kk] * LOG2E, e1 = Em_g[kk + 1] * LOG2E;
        Et2[tid] = make_float2(t0, t1 - t0);
        Ed2[tid] = make_float2(d0, d1 - d0);
        Em2[tid] = make_float2(e0, e1 - e0);
        if (tid < NN) {
            int p = poi_idx[b * NN + tid];
            int pd = (p < 0);
            float la = lat[b * NN + tid], lo = lon[b * NN + tid];
            float cs = cos_small(la * DEG2RADF);
            float pen = pd ? PENAL : 0.f;
            nidx[tid] = make_int2(pd ? NPOIS : p, pd ? 0 : hourw[b * NN + tid]);
            bnfo[tid]  = make_float4(la * KHALF, lo * KHALF, cs,
                                     tmin[b * NN + tid] * TBIN_SC);
            bnfoM[tid] = make_float4(la * KHALF, lo * KHALF, cs, pen);
            jpen[tid] = pen;
        } else {
            // poi_emb[NPOIS] and time_emb[0] are all-zero rows -> x row = 0
            nidx[tid] = make_int2(NPOIS, 0);
            bnfo[tid]  = make_float4(0.f, 0.f, 1.f, 0.f);
            bnfoM[tid] = make_float4(0.f, 0.f, 1.f, PENAL);
            jpen[tid] = PENAL;
        }
    }
    __syncthreads();

    // ---- phase 1: gather x -> xs (bf16, swizzled u32 stores) ----
    for (int idx = tid; idx < 64 * 64; idx += 256) {
        int n = idx >> 6, c2 = idx & 63;       // c2 = dword index within row
        int2 ix = nidx[n];
        float2 pe = ((const float2*)(poi_emb  + (size_t)ix.x * DD))[c2];
        float2 te = ((const float2*)(time_emb + (size_t)ix.y * DD))[c2];
        unsigned pack = (unsigned)f2bf(pe.x + te.x)
                      | ((unsigned)f2bf(pe.y + te.y) << 16);
        ((unsigned*)xs)[n * 64 + (((c2 >> 2) ^ (n & 7)) << 2) + (c2 & 3)] = pack;
    }
    __syncthreads();

    // thread-constant swizzle bases (see comment at swz128)
    const int q8    = (quad ^ (colr & 3)) * 8;
    const int kx    = (colr & 4) * 8;          // ((colr>>2)&1)*32
    const int xbase = colr * 128 + q8;
    const int xe = xbase + kx, xo = xbase - kx;

    // ---- phase 2: Y = x @ Mt^T (MFMA), Mt streamed from L1/L2 ----
    {
        f32x4 accY[2][4];
        #pragma unroll
        for (int ct = 0; ct < 2; ct++)
            #pragma unroll
            for (int mt = 0; mt < 4; mt++) accY[ct][mt] = (f32x4){0.f, 0.f, 0.f, 0.f};
        #pragma unroll
        for (int ks = 0; ks < 4; ks++) {
            const int k0 = ks * 32 + quad * 8;                 // logical (global Mt read)
            const int xoff = ((ks & 1) ? xo : xe) + ks * 32;   // physical LDS offset
            bfrag8 av[4], bv[2];
            #pragma unroll
            for (int mt = 0; mt < 4; mt++)
                av[mt] = *(const bfrag8*)(&xs[xoff + mt * 2048]);
            #pragma unroll
            for (int ct = 0; ct < 2; ct++) {
                int c = wid * 32 + ct * 16 + colr;
                bv[ct] = *(const bfrag8*)(Mtb + (size_t)c * DD + k0);
            }
            #pragma unroll
            for (int ct = 0; ct < 2; ct++)
                #pragma unroll
                for (int mt = 0; mt < 4; mt++)
                    accY[ct][mt] = __builtin_amdgcn_mfma_f32_16x16x32_bf16(
                        av[mt], bv[ct], accY[ct][mt], 0, 0, 0);
        }
        #pragma unroll
        for (int ct = 0; ct < 2; ct++)
            #pragma unroll
            for (int mt = 0; mt < 4; mt++)
                #pragma unroll
                for (int reg = 0; reg < 4; reg++) {
                    int m = mt * 16 + quad * 4 + reg;
                    int c = wid * 32 + ct * 16 + colr;
                    u2.ys[swz128(m, c)] = (short)f2bf(accY[ct][mt][reg]);
                }
    }
    __syncthreads();

    // ---- phase 3: S^T = x @ Y^T (MFMA). C: row=j, col=i=wid*16+colr ----
    const int i = wid * 16 + colr;
    const int ybase = xbase + wid * 2048;
    const int ye = ybase + kx, yo = ybase - kx;
    f32x4 accS[4];
    #pragma unroll
    for (int mt = 0; mt < 4; mt++) accS[mt] = (f32x4){0.f, 0.f, 0.f, 0.f};
    #pragma unroll
    for (int ks = 0; ks < 4; ks++) {           // LOGICAL order: conflict-free
        const int yoff = ((ks & 1) ? yo : ye) + ks * 32;
        const int xoff = ((ks & 1) ? xo : xe) + ks * 32;
        bfrag8 bv = *(const bfrag8*)(&u2.ys[yoff]);
        #pragma unroll
        for (int mt = 0; mt < 4; mt++) {
            bfrag8 av = *(const bfrag8*)(&xs[xoff + mt * 2048]);
            accS[mt] = __builtin_amdgcn_mfma_f32_16x16x32_bf16(
                av, bv, accS[mt], 0, 0, 0);
        }
    }
    __syncthreads();   // ys MFMA reads done; ps may overwrite the union

    // ---- bias + softmax over j (exp2 domain; NO max pass: scores are O(1),
    // pads give exp2(-1e30)=0 exactly; f32 exp2 safe to |s|~120) ----
    {
        const float4 bi = bnfo[i];
        float sv[14];
        #pragma unroll
        for (int mt = 0; mt < 4; mt++) {
            const int nregs = (mt == 3) ? 2 : 4;
            #pragma unroll
            for (int reg = 0; reg < nregs; reg++) {
                int j = mt * 16 + quad * 4 + reg;
                float4 bj = bnfo[j];
                float tb = fabsf(bi.w - bj.w);
                int   kt = (int)tb;
                float ft = fract_asm(tb);
                float2 et = Et2[kt];
                float bt = fmaf(ft, et.y, et.x);
                float du = bi.x - bj.x, dv = bi.y - bj.y;
                float a = fmaf((bi.z * bj.z) * dv, dv, du * du);
                float x = __builtin_amdgcn_sqrtf(a);
                float db = x * fmaf(a, DBIN_C1, DBIN_C0);
                int   kd = (int)db;
                float fd = fract_asm(db);
                float2 ed = Ed2[kd];
                float bd = fmaf(fd, ed.y, ed.x);
                sv[mt * 4 + reg] = (accS[mt][reg] + bt) + (bd + jpen[j]);
            }
        }
        float l = 0.f;
        #pragma unroll
        for (int t = 0; t < 14; t++) {
            float p = exp2_asm(sv[t]);
            sv[t] = p;
            l += p;
        }
        l += __shfl_xor(l, 16, 64);
        l += __shfl_xor(l, 32, 64);
        float rl = __builtin_amdgcn_rcpf(l);
        #pragma unroll
        for (int mt = 0; mt < 4; mt++)
            #pragma unroll
            for (int rp = 0; rp < 2; rp++) {
                int j0 = mt * 16 + quad * 4 + rp * 2;
                unsigned pack;
                if (mt == 3 && rp == 1) {
                    pack = 0u;                 // always-invalid slots: P = 0
                } else {
                    unsigned lo = f2bf(sv[mt * 4 + rp * 2]     * rl);
                    unsigned hi = f2bf(sv[mt * 4 + rp * 2 + 1] * rl);
                    pack = lo | (hi << 16);
                }
                ((unsigned*)u2.ps)[i * 32 + (((j0 >> 3) ^ (i & 7)) << 2) + ((j0 & 7) >> 1)]
                    = pack;
            }
    }
    __syncthreads();

    // ---- phase 4: Z = P @ x (K=64 over j); then accZ -> As (swizzled LDS) ----
    {
        f32x4 accZ[2][4];
        #pragma unroll
        for (int nt = 0; nt < 2; nt++)
            #pragma unroll
            for (int mt = 0; mt < 4; mt++) accZ[nt][mt] = (f32x4){0.f, 0.f, 0.f, 0.f};
        union BF { unsigned u[4]; bfrag8 v; };
        const int pbase = colr * 64 + q8;
        const int pe = pbase + kx, po = pbase - kx;
        #pragma unroll
        for (int ks = 0; ks < 2; ks++) {
            const int k0 = ks * 32 + quad * 8;                 // logical (xs gather)
            const int poff = ((ks & 1) ? po : pe) + ks * 32;   // physical (ps reads)
            bfrag8 av[4];
            #pragma unroll
            for (int mt = 0; mt < 4; mt++)
                av[mt] = *(const bfrag8*)(&u2.ps[poff + mt * 1024]);
            BF bvx[2];
            #pragma unroll
            for (int nt = 0; nt < 2; nt++) {
                int d = wid * 32 + nt * 16 + colr;
                #pragma unroll
                for (int t2 = 0; t2 < 4; t2++) {
                    unsigned lo = (unsigned short)xs[swz128(k0 + 2 * t2,     d)];
                    unsigned hi = (unsigned short)xs[swz128(k0 + 2 * t2 + 1, d)];
                    bvx[nt].u[t2] = lo | (hi << 16);
                }
            }
            #pragma unroll
            for (int nt = 0; nt < 2; nt++)
                #pragma unroll
                for (int mt = 0; mt < 4; mt++)
                    accZ[nt][mt] = __builtin_amdgcn_mfma_f32_16x16x32_bf16(
                        av[mt], bvx[nt].v, accZ[nt][mt], 0, 0, 0);
        }
        __syncthreads();   // all ps reads done; as_ may overwrite the union
        #pragma unroll
        for (int mt = 0; mt < 4; mt++)
            #pragma unroll
            for (int reg = 0; reg < 4; reg++) {
                int ii = mt * 16 + quad * 4 + reg;
                #pragma unroll
                for (int nt = 0; nt < 2; nt++) {
                    int d = wid * 32 + nt * 16 + colr;
                    float zv = (ii < NN) ? accZ[nt][mt][reg] : 0.f;
                    u2.as_[swz128(ii, d)] = (short)f2bf(zv);
                }
            }
    }
    __syncthreads();

    // ---- match part: 8 outer iters × 2 r-tiles.  Each Af LDS read feeds TWO
    // MFMAs (MFMA:DS 2:1, halving the ~10 us Af-read item).  bf0/bf1 are
    // loaded at the TOP of the iteration and DIE at the end of the MFMA
    // cluster (r11 lesson: keeping them live across the bias blocks pushed
    // that region to ~84 arch regs -> spill).  Exposed L2 latency at cluster
    // start is covered by the other 3 waves/SIMD. ----
    const int rL = wid * 16 + colr;

    #pragma unroll 1
    for (int ot = 0; ot < 8; ot++) {
        f32x4 acc0[4], acc1[4];
        #pragma unroll
        for (int mt = 0; mt < 4; mt++) {
            acc0[mt] = (f32x4){0.f, 0.f, 0.f, 0.f};
            acc1[mt] = (f32x4){0.f, 0.f, 0.f, 0.f};
        }
        {
            bfrag8 bf0[4], bf1[4];
            #pragma unroll
            for (int ks = 0; ks < 4; ks++) {
                bf0[ks] = *(const bfrag8*)(Gp + (size_t)((((2 * ot    ) * 16 + wid * 4 + ks) * 64 + lane) << 3));
                bf1[ks] = *(const bfrag8*)(Gp + (size_t)((((2 * ot + 1) * 16 + wid * 4 + ks) * 64 + lane) << 3));
            }
            #pragma unroll
            for (int ks = 0; ks < 4; ks++) {
                const int aoff = ((ks & 1) ? xo : xe) + ks * 32;
                #pragma unroll
                for (int mt = 0; mt < 4; mt++) {
                    bfrag8 af = *(const bfrag8*)(&u2.as_[aoff + mt * 2048]);
                    acc0[mt] = __builtin_amdgcn_mfma_f32_16x16x32_bf16(af, bf0[ks], acc0[mt], 0, 0, 0);
                    acc1[mt] = __builtin_amdgcn_mfma_f32_16x16x32_bf16(af, bf1[ks], acc1[mt], 0, 0, 0);
                }
            }
        }   // bf0/bf1 dead here — bias region holds only acc0/acc1 + temps

        // ---- two bias + softmax-weighted sums (exp2 domain; no max pass;
        // 'half' fully unrolled -> acc select is static) ----
        #pragma unroll
        for (int half = 0; half < 2; half++) {
            const int r  = (2 * ot + half) * 64 + rL;
            const int rc = (r < RR) ? r : (RR - 1);
            float2 cc = ((const float2*)cent)[rc];
            const float rvx = cc.x * KHALF, rvy = cc.y * KHALF;
            const float rvz = cos_small(cc.x * DEG2RADF);
            float l = 0.f, aw = 0.f;
            #pragma unroll
            for (int mt = 0; mt < 4; mt++) {
                const int nregs = (mt == 3) ? 2 : 4;
                #pragma unroll
                for (int reg = 0; reg < nregs; reg++) {
                    int n = mt * 16 + quad * 4 + reg;
                    float4 bn = bnfoM[n];
                    float du = bn.x - rvx, dv = bn.y - rvy;
                    float a = fmaf((bn.z * rvz) * dv, dv, du * du);
                    float x = __builtin_amdgcn_sqrtf(a);
                    float db = x * fmaf(a, DBIN_C1, DBIN_C0);
                    int   kd = (int)db;
                    float fd = fract_asm(db);
                    float2 ed = Em2[kd];
                    float bias = fmaf(fd, ed.y, ed.x);
                    float av_ = half ? acc1[mt][reg] : acc0[mt][reg];
                    float sc = (av_ + bias) + bn.w;
                    float p = exp2_asm(sc);      // pad slots: exp2(-1e30) = 0
                    l += p;
                    aw = fmaf(p, sc, aw);        // fma(0, -1e30, aw) = aw exactly
                }
            }
            l  += __shfl_xor(l, 16, 64); aw += __shfl_xor(aw, 16, 64);
            l  += __shfl_xor(l, 32, 64); aw += __shfl_xor(aw, 32, 64);
            if (quad == 0 && r < RR)
                out[(size_t)b * RR + r] = aw * __builtin_amdgcn_rcpf(l) * LN2;
        }
    }
}

extern "C" void kernel_launch(void* const* d_in, const int* in_sizes, int n_in,
                              void* d_out, int out_size, void* d_ws, size_t ws_size,
                              hipStream_t stream) {
    const int*   poi_idx  = (const int*)d_in[0];
    const int*   hourw    = (const int*)d_in[1];
    const float* lat      = (const float*)d_in[2];
    const float* lon      = (const float*)d_in[3];
    const float* tmin     = (const float*)d_in[4];
    const float* cent     = (const float*)d_in[5];
    const float* poi_emb  = (const float*)d_in[6];
    const float* time_emb = (const float*)d_in[7];
    const float* E_t      = (const float*)d_in[8];
    const float* E_d      = (const float*)d_in[9];
    const float* E_dm     = (const float*)d_in[10];
    const float* Remb     = (const float*)d_in[11];
    const float* Wq       = (const float*)d_in[12];
    const float* Wk       = (const float*)d_in[13];
    const float* Wv       = (const float*)d_in[14];
    float* out            = (float*)d_out;

    unsigned short* Mtb = (unsigned short*)d_ws;            // 128*128 bf16 (32 KB)
    unsigned short* Gpb = Mtb + DD * DD;                    // 1024*128 bf16 (256 KB, frag order)

    prep_mg<<<dim3(DD + 1024), DD, 0, stream>>>(Wq, Wk, Wv, Remb, Mtb, Gpb);
    stan_fused<<<dim3(BB), 256, 0, stream>>>(poi_idx, hourw, lat, lon, tmin,
                                             poi_emb, time_emb, E_t, E_d, E_dm,
                                             Mtb, Gpb, cent, out);
}

// Round 13
// 153.324 us; speedup vs baseline: 1.4215x; 1.0603x over previous
//
#include <hip/hip_runtime.h>
#include <hip/hip_bf16.h>
#include <math.h>

// ---- problem constants ----
constexpr int BB    = 1024;
constexpr int NN    = 50;
constexpr int RR    = 1000;
constexpr int DD    = 128;
constexpr int NPOIS = 50000;
#define DEG2RADF  0.017453292519943295f
#define KHALF     0.008726646259971648f   // DEG2RAD/2
#define RSQRTD    0.08838834764831845f    // 1/sqrt(128)
#define LOG2E     1.4426950408889634f
#define LN2       0.6931471805599453f
#define DBIN_C0   4013.7373f
#define DBIN_C1   668.95621f
#define TBIN_SC   0.00625f                // 63/10080
#define PENAL     -1.0e30f                // additive mask sentinel

typedef __attribute__((ext_vector_type(8))) short bfrag8;
typedef __attribute__((ext_vector_type(4))) float f32x4;

// XOR-swizzled LDS tile addressing (shorts). Row stride 128 shorts;
// 16-B block j of row r lives at physical block j ^ (r & 7).
// All MFMA fragment-row indices are ≡ colr (mod 8): for logical k-chunk ks the
// physical offset is base+kx+ks*32 (even ks) / base-kx+ks*32 (odd ks), with
// base = colr*128 + 8*(quad^(colr&3)), kx = 32*((colr>>2)&1).  Iterate
// LOGICAL ks (round 1 measured: physical-order iteration doubles bank
// conflicts).
// REGISTER-BUDGET NOTE (rounds 8-12 measured): at __launch_bounds__(256,4)
// budget = 128 unified = 64 arch + 64 acc; the allocator pins arch at 64 and
// spills/demotes rather than allocating 65..128 arch.
//   r8:  Xf hoist + unroll-2 (demand >>128)      -> scratch, FETCH 460 MB
//   r9:  Af[4][4] hoist (demand ~132)            -> Af demoted to LDS reads
//   r11: bf0/bf1 (32) live across bias           -> spill, FETCH 248 MB
//   r12: acc1 (16) live across half-0 bias       -> spill, WRITE +16 MB
// Calibration: ~16 extra arch live across the bias region is OK (r10's bfv),
// ~32 is not; a 2nd accumulator set is demoted.  Every Af-sharing scheme
// needs >=16 cross-bias live regs -> all spill.  This kernel (r10 structure)
// is the measured optimum of the structure: dur ~65 us, FETCH 14.4 MB.
__device__ __forceinline__ int swz128(int row, int k) {
    return row * 128 + ((((k) >> 3) ^ (row & 7)) << 3) + (k & 7);
}

__device__ __forceinline__ unsigned short f2bf(float x) {
    union { __hip_bfloat16 h; unsigned short u; } cv;
    cv.h = __float2bfloat16(x);
    return cv.u;
}

__device__ __forceinline__ float exp2_asm(float x) {   // v_exp_f32: D = 2^S0
    float r;
    asm("v_exp_f32 %0, %1" : "=v"(r) : "v"(x));
    return r;
}

__device__ __forceinline__ float fract_asm(float x) {  // D = S0 - floor(S0)
    float r;
    asm("v_fract_f32 %0, %1" : "=v"(r) : "v"(x));
    return r;
}

__device__ __forceinline__ float cos_small(float x) {
    float x2 = x * x;
    return 1.0f - 0.5f * x2 + 0.041666667f * x2 * x2;
}

// ---- precompute (merged): Mt and Gp, both bf16 with LOG2E/sqrt(D) folded ----
// Gp in MFMA B-fragment order: Gp[rt][wid][ks][lane][8], lane = quad*16+colr,
// r = rt*64 + wid*16 + colr, k = ks*32 + quad*8 + k7. Rows 1000..1023 zeroed.
__global__ void prep_mg(const float* __restrict__ Wq, const float* __restrict__ Wk,
                        const float* __restrict__ Wv, const float* __restrict__ Re,
                        unsigned short* __restrict__ Mt, unsigned short* __restrict__ Gp) {
    int k = threadIdx.x;
    if (blockIdx.x < DD) {
        int c = blockIdx.x;
        float s0 = 0.f, s1 = 0.f, s2 = 0.f, s3 = 0.f;
        for (int d = 0; d < DD; d += 4) {
            s0 += Wq[(d + 0) * DD + k] * Wk[(d + 0) * DD + c];
            s1 += Wq[(d + 1) * DD + k] * Wk[(d + 1) * DD + c];
            s2 += Wq[(d + 2) * DD + k] * Wk[(d + 2) * DD + c];
            s3 += Wq[(d + 3) * DD + k] * Wk[(d + 3) * DD + c];
        }
        Mt[c * DD + k] = f2bf((s0 + s1 + s2 + s3) * (RSQRTD * LOG2E));
    } else {
        int r = blockIdx.x - DD;
        float val = 0.f;
        if (r < RR) {
            float s0 = 0.f, s1 = 0.f, s2 = 0.f, s3 = 0.f;
            for (int d = 0; d < DD; d += 4) {
                s0 += Wv[(d + 0) * DD + k] * Re[r * DD + d + 0];
                s1 += Wv[(d + 1) * DD + k] * Re[r * DD + d + 1];
                s2 += Wv[(d + 2) * DD + k] * Re[r * DD + d + 2];
                s3 += Wv[(d + 3) * DD + k] * Re[r * DD + d + 3];
            }
            val = (s0 + s1 + s2 + s3) * (RSQRTD * LOG2E);
        }
        int rt = r >> 6, widr = (r >> 4) & 3, colr = r & 15;
        int ks = k >> 5, quad = (k >> 3) & 3, k7 = k & 7;
        int lane = quad * 16 + colr;
        Gp[((((rt * 16 + widr * 4 + ks) * 64) + lane) << 3) + k7] = f2bf(val);
    }
}

// ---- fused: per-b attention (4 MFMA phases) + match (16 rt-tiles) ----
// Z never touches HBM: accZ registers -> swizzled LDS (reusing the dead
// ys/ps union as As) -> match loop.
__global__ __launch_bounds__(256, 4) void stan_fused(
    const int* __restrict__ poi_idx, const int* __restrict__ hourw,
    const float* __restrict__ lat, const float* __restrict__ lon,
    const float* __restrict__ tmin,
    const float* __restrict__ poi_emb, const float* __restrict__ time_emb,
    const float* __restrict__ Et_g, const float* __restrict__ Ed_g,
    const float* __restrict__ Em_g,
    const unsigned short* __restrict__ Mtb, const unsigned short* __restrict__ Gp,
    const float* __restrict__ cent, float* __restrict__ out) {
    __shared__ short xs[64 * 128];             // x bf16, swizzled, 16 KB
    __shared__ union {
        short ys[64 * 128];                    // Y bf16, swizzled, 16 KB
        short ps[64 * 64];                     // P bf16, swizzled
        short as_[64 * 128];                   // Z bf16, swizzled (match A-tile)
    } u2;
    __shared__ float2 Et2[64], Ed2[64], Em2[64];  // (e, de) * LOG2E
    __shared__ float4 bnfo[64];                // (latk, lonk, cos, t*TBIN_SC)
    __shared__ float4 bnfoM[64];               // (latk, lonk, cos, pen) for match
    __shared__ float  jpen[64];                // 0 valid / -1e30 pad
    __shared__ int2   nidx[64];                // (poi row, hour row) for gather

    const int b = blockIdx.x, tid = threadIdx.x;
    const int wid = tid >> 6, lane = tid & 63;
    const int quad = lane >> 4, colr = lane & 15;

    if (tid < 64) {
        int kk = tid > 62 ? 62 : tid;
        float t0 = Et_g[kk] * LOG2E, t1 = Et_g[kk + 1] * LOG2E;
        float d0 = Ed_g[kk] * LOG2E, d1 = Ed_g[kk + 1] * LOG2E;
        float e0 = Em_g[kk] * LOG2E, e1 = Em_g[kk + 1] * LOG2E;
        Et2[tid] = make_float2(t0, t1 - t0);
        Ed2[tid] = make_float2(d0, d1 - d0);
        Em2[tid] = make_float2(e0, e1 - e0);
        if (tid < NN) {
            int p = poi_idx[b * NN + tid];
            int pd = (p < 0);
            float la = lat[b * NN + tid], lo = lon[b * NN + tid];
            float cs = cos_small(la * DEG2RADF);
            float pen = pd ? PENAL : 0.f;
            nidx[tid] = make_int2(pd ? NPOIS : p, pd ? 0 : hourw[b * NN + tid]);
            bnfo[tid]  = make_float4(la * KHALF, lo * KHALF, cs,
                                     tmin[b * NN + tid] * TBIN_SC);
            bnfoM[tid] = make_float4(la * KHALF, lo * KHALF, cs, pen);
            jpen[tid] = pen;
        } else {
            // poi_emb[NPOIS] and time_emb[0] are all-zero rows -> x row = 0
            nidx[tid] = make_int2(NPOIS, 0);
            bnfo[tid]  = make_float4(0.f, 0.f, 1.f, 0.f);
            bnfoM[tid] = make_float4(0.f, 0.f, 1.f, PENAL);
            jpen[tid] = PENAL;
        }
    }
    __syncthreads();

    // ---- phase 1: gather x -> xs (bf16, swizzled u32 stores) ----
    for (int idx = tid; idx < 64 * 64; idx += 256) {
        int n = idx >> 6, c2 = idx & 63;       // c2 = dword index within row
        int2 ix = nidx[n];
        float2 pe = ((const float2*)(poi_emb  + (size_t)ix.x * DD))[c2];
        float2 te = ((const float2*)(time_emb + (size_t)ix.y * DD))[c2];
        unsigned pack = (unsigned)f2bf(pe.x + te.x)
                      | ((unsigned)f2bf(pe.y + te.y) << 16);
        ((unsigned*)xs)[n * 64 + (((c2 >> 2) ^ (n & 7)) << 2) + (c2 & 3)] = pack;
    }
    __syncthreads();

    // thread-constant swizzle bases (see comment at swz128)
    const int q8    = (quad ^ (colr & 3)) * 8;
    const int kx    = (colr & 4) * 8;          // ((colr>>2)&1)*32
    const int xbase = colr * 128 + q8;
    const int xe = xbase + kx, xo = xbase - kx;

    // ---- phase 2: Y = x @ Mt^T (MFMA), Mt streamed from L1/L2 ----
    {
        f32x4 accY[2][4];
        #pragma unroll
        for (int ct = 0; ct < 2; ct++)
            #pragma unroll
            for (int mt = 0; mt < 4; mt++) accY[ct][mt] = (f32x4){0.f, 0.f, 0.f, 0.f};
        #pragma unroll
        for (int ks = 0; ks < 4; ks++) {
            const int k0 = ks * 32 + quad * 8;                 // logical (global Mt read)
            const int xoff = ((ks & 1) ? xo : xe) + ks * 32;   // physical LDS offset
            bfrag8 av[4], bv[2];
            #pragma unroll
            for (int mt = 0; mt < 4; mt++)
                av[mt] = *(const bfrag8*)(&xs[xoff + mt * 2048]);
            #pragma unroll
            for (int ct = 0; ct < 2; ct++) {
                int c = wid * 32 + ct * 16 + colr;
                bv[ct] = *(const bfrag8*)(Mtb + (size_t)c * DD + k0);
            }
            #pragma unroll
            for (int ct = 0; ct < 2; ct++)
                #pragma unroll
                for (int mt = 0; mt < 4; mt++)
                    accY[ct][mt] = __builtin_amdgcn_mfma_f32_16x16x32_bf16(
                        av[mt], bv[ct], accY[ct][mt], 0, 0, 0);
        }
        #pragma unroll
        for (int ct = 0; ct < 2; ct++)
            #pragma unroll
            for (int mt = 0; mt < 4; mt++)
                #pragma unroll
                for (int reg = 0; reg < 4; reg++) {
                    int m = mt * 16 + quad * 4 + reg;
                    int c = wid * 32 + ct * 16 + colr;
                    u2.ys[swz128(m, c)] = (short)f2bf(accY[ct][mt][reg]);
                }
    }
    __syncthreads();

    // ---- phase 3: S^T = x @ Y^T (MFMA). C: row=j, col=i=wid*16+colr ----
    const int i = wid * 16 + colr;
    const int ybase = xbase + wid * 2048;
    const int ye = ybase + kx, yo = ybase - kx;
    f32x4 accS[4];
    #pragma unroll
    for (int mt = 0; mt < 4; mt++) accS[mt] = (f32x4){0.f, 0.f, 0.f, 0.f};
    #pragma unroll
    for (int ks = 0; ks < 4; ks++) {           // LOGICAL order: conflict-free
        const int yoff = ((ks & 1) ? yo : ye) + ks * 32;
        const int xoff = ((ks & 1) ? xo : xe) + ks * 32;
        bfrag8 bv = *(const bfrag8*)(&u2.ys[yoff]);
        #pragma unroll
        for (int mt = 0; mt < 4; mt++) {
            bfrag8 av = *(const bfrag8*)(&xs[xoff + mt * 2048]);
            accS[mt] = __builtin_amdgcn_mfma_f32_16x16x32_bf16(
                av, bv, accS[mt], 0, 0, 0);
        }
    }
    __syncthreads();   // ys MFMA reads done; ps may overwrite the union

    // ---- bias + softmax over j (exp2 domain; NO max pass: scores are O(1),
    // pads give exp2(-1e30)=0 exactly; f32 exp2 safe to |s|~120) ----
    {
        const float4 bi = bnfo[i];
        float sv[14];
        #pragma unroll
        for (int mt = 0; mt < 4; mt++) {
            const int nregs = (mt == 3) ? 2 : 4;
            #pragma unroll
            for (int reg = 0; reg < nregs; reg++) {
                int j = mt * 16 + quad * 4 + reg;
                float4 bj = bnfo[j];
                float tb = fabsf(bi.w - bj.w);
                int   kt = (int)tb;
                float ft = fract_asm(tb);
                float2 et = Et2[kt];
                float bt = fmaf(ft, et.y, et.x);
                float du = bi.x - bj.x, dv = bi.y - bj.y;
                float a = fmaf((bi.z * bj.z) * dv, dv, du * du);
                float x = __builtin_amdgcn_sqrtf(a);
                float db = x * fmaf(a, DBIN_C1, DBIN_C0);
                int   kd = (int)db;
                float fd = fract_asm(db);
                float2 ed = Ed2[kd];
                float bd = fmaf(fd, ed.y, ed.x);
                sv[mt * 4 + reg] = (accS[mt][reg] + bt) + (bd + jpen[j]);
            }
        }
        float l = 0.f;
        #pragma unroll
        for (int t = 0; t < 14; t++) {
            float p = exp2_asm(sv[t]);
            sv[t] = p;
            l += p;
        }
        l += __shfl_xor(l, 16, 64);
        l += __shfl_xor(l, 32, 64);
        float rl = __builtin_amdgcn_rcpf(l);
        #pragma unroll
        for (int mt = 0; mt < 4; mt++)
            #pragma unroll
            for (int rp = 0; rp < 2; rp++) {
                int j0 = mt * 16 + quad * 4 + rp * 2;
                unsigned pack;
                if (mt == 3 && rp == 1) {
                    pack = 0u;                 // always-invalid slots: P = 0
                } else {
                    unsigned lo = f2bf(sv[mt * 4 + rp * 2]     * rl);
                    unsigned hi = f2bf(sv[mt * 4 + rp * 2 + 1] * rl);
                    pack = lo | (hi << 16);
                }
                ((unsigned*)u2.ps)[i * 32 + (((j0 >> 3) ^ (i & 7)) << 2) + ((j0 & 7) >> 1)]
                    = pack;
            }
    }
    __syncthreads();

    // ---- phase 4: Z = P @ x (K=64 over j); then accZ -> As (swizzled LDS) ----
    {
        f32x4 accZ[2][4];
        #pragma unroll
        for (int nt = 0; nt < 2; nt++)
            #pragma unroll
            for (int mt = 0; mt < 4; mt++) accZ[nt][mt] = (f32x4){0.f, 0.f, 0.f, 0.f};
        union BF { unsigned u[4]; bfrag8 v; };
        const int pbase = colr * 64 + q8;
        const int pe = pbase + kx, po = pbase - kx;
        #pragma unroll
        for (int ks = 0; ks < 2; ks++) {
            const int k0 = ks * 32 + quad * 8;                 // logical (xs gather)
            const int poff = ((ks & 1) ? po : pe) + ks * 32;   // physical (ps reads)
            bfrag8 av[4];
            #pragma unroll
            for (int mt = 0; mt < 4; mt++)
                av[mt] = *(const bfrag8*)(&u2.ps[poff + mt * 1024]);
            BF bvx[2];
            #pragma unroll
            for (int nt = 0; nt < 2; nt++) {
                int d = wid * 32 + nt * 16 + colr;
                #pragma unroll
                for (int t2 = 0; t2 < 4; t2++) {
                    unsigned lo = (unsigned short)xs[swz128(k0 + 2 * t2,     d)];
                    unsigned hi = (unsigned short)xs[swz128(k0 + 2 * t2 + 1, d)];
                    bvx[nt].u[t2] = lo | (hi << 16);
                }
            }
            #pragma unroll
            for (int nt = 0; nt < 2; nt++)
                #pragma unroll
                for (int mt = 0; mt < 4; mt++)
                    accZ[nt][mt] = __builtin_amdgcn_mfma_f32_16x16x32_bf16(
                        av[mt], bvx[nt].v, accZ[nt][mt], 0, 0, 0);
        }
        __syncthreads();   // all ps reads done; as_ may overwrite the union
        #pragma unroll
        for (int mt = 0; mt < 4; mt++)
            #pragma unroll
            for (int reg = 0; reg < 4; reg++) {
                int ii = mt * 16 + quad * 4 + reg;
                #pragma unroll
                for (int nt = 0; nt < 2; nt++) {
                    int d = wid * 32 + nt * 16 + colr;
                    float zv = (ii < NN) ? accZ[nt][mt][reg] : 0.f;
                    u2.as_[swz128(ii, d)] = (short)f2bf(zv);
                }
            }
    }
    __syncthreads();

    // ---- match part: 16 rt-tiles, single-buffered bfv (reloaded right after
    // the MFMA cluster; 16 live regs across bias is the measured-safe max),
    // fused bias+exp2+accumulate pass (no s[] array).  Af stays in LDS — all
    // register-hoist variants spill (see pressure note). ----
    bfrag8 bfv[4];
    #pragma unroll
    for (int ks = 0; ks < 4; ks++)
        bfv[ks] = *(const bfrag8*)(Gp + (size_t)(((wid * 4 + ks) * 64 + lane) << 3));

    const int rL = wid * 16 + colr;

    #pragma unroll 1
    for (int it = 0; it < 16; it++) {
        f32x4 acc[4];
        #pragma unroll
        for (int mt = 0; mt < 4; mt++) acc[mt] = (f32x4){0.f, 0.f, 0.f, 0.f};
        #pragma unroll
        for (int ks = 0; ks < 4; ks++) {
            const int aoff = ((ks & 1) ? xo : xe) + ks * 32;
            #pragma unroll
            for (int mt = 0; mt < 4; mt++) {
                bfrag8 af = *(const bfrag8*)(&u2.as_[aoff + mt * 2048]);
                acc[mt] = __builtin_amdgcn_mfma_f32_16x16x32_bf16(
                    af, bfv[ks], acc[mt], 0, 0, 0);
            }
        }

        // bfv is dead now — reload it directly for the next tile (no double
        // buffer; loads fly under the ~500-cyc bias/softmax below)
        {
            const int rtn = (it < 15) ? it + 1 : it;
            #pragma unroll
            for (int ks = 0; ks < 4; ks++)
                bfv[ks] = *(const bfrag8*)(Gp + (size_t)(((rtn * 16 + wid * 4 + ks) * 64 + lane) << 3));
        }

        const int r  = it * 64 + rL;
        const int rc = (r < RR) ? r : (RR - 1);
        float2 cc = ((const float2*)cent)[rc];
        const float rvx = cc.x * KHALF, rvy = cc.y * KHALF;
        const float rvz = cos_small(cc.x * DEG2RADF);

        // ---- bias + softmax-weighted sum, fused single pass (exp2 domain;
        // no max pass) ----
        float l = 0.f, aw = 0.f;
        #pragma unroll
        for (int mt = 0; mt < 4; mt++) {
            const int nregs = (mt == 3) ? 2 : 4;
            #pragma unroll
            for (int reg = 0; reg < nregs; reg++) {
                int n = mt * 16 + quad * 4 + reg;
                float4 bn = bnfoM[n];
                float du = bn.x - rvx, dv = bn.y - rvy;
                float a = fmaf((bn.z * rvz) * dv, dv, du * du);
                float x = __builtin_amdgcn_sqrtf(a);
                float db = x * fmaf(a, DBIN_C1, DBIN_C0);
                int   kd = (int)db;
                float fd = fract_asm(db);
                float2 ed = Em2[kd];
                float bias = fmaf(fd, ed.y, ed.x);
                float sc = (acc[mt][reg] + bias) + bn.w;
                float p = exp2_asm(sc);          // pad slots: exp2(-1e30) = 0
                l += p;
                aw = fmaf(p, sc, aw);            // fma(0, -1e30, aw) = aw exactly
            }
        }
        l  += __shfl_xor(l, 16, 64); aw += __shfl_xor(aw, 16, 64);
        l  += __shfl_xor(l, 32, 64); aw += __shfl_xor(aw, 32, 64);
        if (quad == 0 && r < RR)
            out[(size_t)b * RR + r] = aw * __builtin_amdgcn_rcpf(l) * LN2;
    }
}

extern "C" void kernel_launch(void* const* d_in, const int* in_sizes, int n_in,
                              void* d_out, int out_size, void* d_ws, size_t ws_size,
                              hipStream_t stream) {
    const int*   poi_idx  = (const int*)d_in[0];
    const int*   hourw    = (const int*)d_in[1];
    const float* lat      = (const float*)d_in[2];
    const float* lon      = (const float*)d_in[3];
    const float* tmin     = (const float*)d_in[4];
    const float* cent     = (const float*)d_in[5];
    const float* poi_emb  = (const float*)d_in[6];
    const float* time_emb = (const float*)d_in[7];
    const float* E_t      = (const float*)d_in[8];
    const float* E_d      = (const float*)d_in[9];
    const float* E_dm     = (const float*)d_in[10];
    const float* Remb     = (const float*)d_in[11];
    const float* Wq       = (const float*)d_in[12];
    const float* Wk       = (const float*)d_in[13];
    const float* Wv       = (const float*)d_in[14];
    float* out            = (float*)d_out;

    unsigned short* Mtb = (unsigned short*)d_ws;            // 128*128 bf16 (32 KB)
    unsigned short* Gpb = Mtb + DD * DD;                    // 1024*128 bf16 (256 KB, frag order)

    prep_mg<<<dim3(DD + 1024), DD, 0, stream>>>(Wq, Wk, Wv, Remb, Mtb, Gpb);
    stan_fused<<<dim3(BB), 256, 0, stream>>>(poi_idx, hourw, lat, lon, tmin,
                                             poi_emb, time_emb, E_t, E_d, E_dm,
                                             Mtb, Gpb, cent, out);
}